// Round 11
// baseline (267.243 us; speedup 1.0000x reference)
//
#include <hip/hip_runtime.h>

#define N_NODES 100000
#define N_EDGES 600000
#define EMBED_DIM 128
#define EPSF 1e-12f

#define SCAN_NBLK ((N_NODES + 255) / 256)   // 391

// ---------------- CSR build ----------------

__global__ void hist_kernel(const int* __restrict__ head, int* __restrict__ cnt, int E) {
    int e = blockIdx.x * blockDim.x + threadIdx.x;
    if (e < E) atomicAdd(&cnt[head[e]], 1);
}

// Pass 1: per-block sums of cnt
__global__ void scan_part(const int* __restrict__ cnt, int* __restrict__ bsum, int N) {
    __shared__ int lds[256];
    const int t = threadIdx.x;
    const int i = blockIdx.x * 256 + t;
    lds[t] = (i < N) ? cnt[i] : 0;
    __syncthreads();
    for (int off = 128; off; off >>= 1) {
        if (t < off) lds[t] += lds[t + off];
        __syncthreads();
    }
    if (t == 0) bsum[blockIdx.x] = lds[0];
}

// Pass 2: single small block turns bsum into exclusive block offsets (nb <= 512)
__global__ void scan_bsum(int* __restrict__ bsum, int nb) {
    __shared__ int lds[512];
    const int t = threadIdx.x;
    const int v = (t < nb) ? bsum[t] : 0;
    lds[t] = v;
    __syncthreads();
    for (int off = 1; off < 512; off <<= 1) {
        int u = (t >= off) ? lds[t - off] : 0;
        __syncthreads();
        lds[t] += u;
        __syncthreads();
    }
    if (t < nb) bsum[t] = lds[t] - v;   // exclusive
}

// Pass 3: block-local exclusive scan + block offset -> row_ptr
__global__ void scan_final(const int* __restrict__ cnt, const int* __restrict__ bsum,
                           int* __restrict__ row_ptr, int N) {
    __shared__ int lds[256];
    const int t = threadIdx.x;
    const int i = blockIdx.x * 256 + t;
    const int v = (i < N) ? cnt[i] : 0;
    lds[t] = v;
    __syncthreads();
    for (int off = 1; off < 256; off <<= 1) {
        int u = (t >= off) ? lds[t - off] : 0;
        __syncthreads();
        lds[t] += u;
        __syncthreads();
    }
    const int excl = lds[t] - v + bsum[blockIdx.x];
    if (i < N) row_ptr[i] = excl;
    if (i == N - 1) row_ptr[N] = excl + v;
}

// Scatter each edge into its CSR slot as packed (tail | rel<<20).
__global__ void fill_kernel(const int* __restrict__ head, const int* __restrict__ tail,
                            const int* __restrict__ etype, const int* __restrict__ row_ptr,
                            int* __restrict__ fill, int* __restrict__ packed, int E) {
    int e = blockIdx.x * blockDim.x + threadIdx.x;
    if (e < E) {
        int h    = head[e];
        int slot = row_ptr[h] + atomicAdd(&fill[h], 1);
        packed[slot] = tail[e] | (etype[e] << 20);
    }
}

// ---------------- fused hop ----------------
// One wave per node, 4 groups x 16 lanes; group g handles edges g, g+4, ...
// (4 independent row gathers in flight per wave). Lane p (0..15) owns dims
// [8p, 8p+8) via two float4 loads.
//
// CORRECTNESS NOTE: the broadcast loop trip count is WAVE-UNIFORM
// (niter = ceil(d0/4)) so every __shfl executes with all 64 lanes active.
// A divergent `for (e=g; e<d0; e+=4)` loop breaks for deg>=17: ds_bpermute
// sources from exec-off lanes (groups that exited early) return garbage.
// __shfl is `convergent`, so the compiler cannot sink it into the guarded
// body. Only the gather+FMA is predicated on e < d0.

template <bool FIRST>
__global__ __launch_bounds__(256) void hop_kernel(
    const float* __restrict__ x, const float* __restrict__ rel,
    const int* __restrict__ row_ptr, const int* __restrict__ packed,
    const float* __restrict__ base,   // ego (FIRST only)
    float* __restrict__ xn, float* __restrict__ res, int N) {

    const int wid  = (int)((blockIdx.x * blockDim.x + threadIdx.x) >> 6);
    const int lane = threadIdx.x & 63;
    if (wid >= N) return;

    const int beg = row_ptr[wid];
    const int deg = row_ptr[wid + 1] - beg;

    const int g = lane >> 4;   // edge group (0..3)
    const int p = lane & 15;   // dim slot: owns dims [8p, 8p+8)

    const float4* __restrict__ x4   = (const float4*)x;
    const float4* __restrict__ rel4 = (const float4*)rel;

    // preload up to 64 packed entries, one per lane (coalesced)
    const int d0 = min(deg, 64);
    const int pv = (lane < d0) ? packed[beg + lane] : 0;

    float4 accA = make_float4(0.f, 0.f, 0.f, 0.f);
    float4 accB = make_float4(0.f, 0.f, 0.f, 0.f);

    const int niter = (d0 + 3) >> 2;   // wave-uniform trip count
    for (int i = 0; i < niter; ++i) {
        const int e  = g + (i << 2);          // e <= 63 always (d0 <= 64)
        const int pk = __shfl(pv, e, 64);     // full-exec broadcast
        if (e < d0) {
            const int t = pk & 0xFFFFF;
            const int r = pk >> 20;
            const float4 xa = x4[t * 32 + 2 * p];
            const float4 xb = x4[t * 32 + 2 * p + 1];
            const float4 ra = rel4[r * 32 + 2 * p];
            const float4 rb = rel4[r * 32 + 2 * p + 1];
            accA.x = fmaf(xa.x, ra.x, accA.x);
            accA.y = fmaf(xa.y, ra.y, accA.y);
            accA.z = fmaf(xa.z, ra.z, accA.z);
            accA.w = fmaf(xa.w, ra.w, accA.w);
            accB.x = fmaf(xb.x, rb.x, accB.x);
            accB.y = fmaf(xb.y, rb.y, accB.y);
            accB.z = fmaf(xb.z, rb.z, accB.z);
            accB.w = fmaf(xb.w, rb.w, accB.w);
        }
    }
    // rare tail: degree > 64 (direct packed loads, no shfl)
    for (int e = 64 + g; e < deg; e += 4) {
        const int pk = packed[beg + e];
        const int t = pk & 0xFFFFF;
        const int r = pk >> 20;
        const float4 xa = x4[t * 32 + 2 * p];
        const float4 xb = x4[t * 32 + 2 * p + 1];
        const float4 ra = rel4[r * 32 + 2 * p];
        const float4 rb = rel4[r * 32 + 2 * p + 1];
        accA.x = fmaf(xa.x, ra.x, accA.x);
        accA.y = fmaf(xa.y, ra.y, accA.y);
        accA.z = fmaf(xa.z, ra.z, accA.z);
        accA.w = fmaf(xa.w, ra.w, accA.w);
        accB.x = fmaf(xb.x, rb.x, accB.x);
        accB.y = fmaf(xb.y, rb.y, accB.y);
        accB.z = fmaf(xb.z, rb.z, accB.z);
        accB.w = fmaf(xb.w, rb.w, accB.w);
    }

    // fold the 4 edge groups (lanes with equal p then hold the full sum)
    accA.x += __shfl_xor(accA.x, 16, 64); accA.x += __shfl_xor(accA.x, 32, 64);
    accA.y += __shfl_xor(accA.y, 16, 64); accA.y += __shfl_xor(accA.y, 32, 64);
    accA.z += __shfl_xor(accA.z, 16, 64); accA.z += __shfl_xor(accA.z, 32, 64);
    accA.w += __shfl_xor(accA.w, 16, 64); accA.w += __shfl_xor(accA.w, 32, 64);
    accB.x += __shfl_xor(accB.x, 16, 64); accB.x += __shfl_xor(accB.x, 32, 64);
    accB.y += __shfl_xor(accB.y, 16, 64); accB.y += __shfl_xor(accB.y, 32, 64);
    accB.z += __shfl_xor(accB.z, 16, 64); accB.z += __shfl_xor(accB.z, 32, 64);
    accB.w += __shfl_xor(accB.w, 16, 64); accB.w += __shfl_xor(accB.w, 32, 64);

    const float inv = 1.0f / (float)max(deg, 1);
    accA.x *= inv; accA.y *= inv; accA.z *= inv; accA.w *= inv;
    accB.x *= inv; accB.y *= inv; accB.z *= inv; accB.w *= inv;

    // sum of squares: 8 local dims, then fold across the 16 dim slots
    float ss = accA.x * accA.x + accA.y * accA.y + accA.z * accA.z + accA.w * accA.w
             + accB.x * accB.x + accB.y * accB.y + accB.z * accB.z + accB.w * accB.w;
    #pragma unroll
    for (int off = 8; off; off >>= 1) ss += __shfl_xor(ss, off, 64);

    const float scale = 1.0f / fmaxf(sqrtf(ss), EPSF);
    const float4 v0 = make_float4(accA.x * scale, accA.y * scale,
                                  accA.z * scale, accA.w * scale);
    const float4 v1 = make_float4(accB.x * scale, accB.y * scale,
                                  accB.z * scale, accB.w * scale);

    if (g == 0) {
        const int idx = wid * 32 + 2 * p;   // float4 index
        ((float4*)xn)[idx]     = v0;
        ((float4*)xn)[idx + 1] = v1;
        float4* res4 = (float4*)res;
        if (FIRST) {
            const float4 b0 = ((const float4*)base)[idx];
            const float4 b1 = ((const float4*)base)[idx + 1];
            res4[idx]     = make_float4(b0.x + v0.x, b0.y + v0.y, b0.z + v0.z, b0.w + v0.w);
            res4[idx + 1] = make_float4(b1.x + v1.x, b1.y + v1.y, b1.z + v1.z, b1.w + v1.w);
        } else {
            const float4 r0 = res4[idx];
            const float4 r1 = res4[idx + 1];
            res4[idx]     = make_float4(r0.x + v0.x, r0.y + v0.y, r0.z + v0.z, r0.w + v0.w);
            res4[idx + 1] = make_float4(r1.x + v1.x, r1.y + v1.y, r1.z + v1.z, r1.w + v1.w);
        }
    }
}

// ---------------- launch ----------------

extern "C" void kernel_launch(void* const* d_in, const int* in_sizes, int n_in,
                              void* d_out, int out_size, void* d_ws, size_t ws_size,
                              hipStream_t stream) {
    const float* ego   = (const float*)d_in[0];
    const int*   eidx  = (const int*)d_in[1];   // [2, E]: row 0 = head, row 1 = tail
    const int*   etype = (const int*)d_in[2];
    const float* rel   = (const float*)d_in[3];
    // d_in[4] = dropout scalar (0 in eval) -> ignored

    const int* head = eidx;
    const int* tail = eidx + N_EDGES;
    float* res = (float*)d_out;

    // workspace layout
    char* ws = (char*)d_ws;
    int* cnt     = (int*)ws;  ws += (size_t)N_NODES * sizeof(int);
    int* row_ptr = (int*)ws;  ws += (size_t)(N_NODES + 1) * sizeof(int);
    int* fill    = (int*)ws;  ws += (size_t)N_NODES * sizeof(int);
    int* packed  = (int*)ws;  ws += (size_t)N_EDGES * sizeof(int);
    int* bsum    = (int*)ws;  ws += (size_t)SCAN_NBLK * sizeof(int);
    ws = (char*)(((uintptr_t)ws + 255) & ~(uintptr_t)255);
    float* x0 = (float*)ws;   ws += (size_t)N_NODES * EMBED_DIM * sizeof(float);
    float* x1 = (float*)ws;

    hipMemsetAsync(cnt,  0, (size_t)N_NODES * sizeof(int), stream);
    hipMemsetAsync(fill, 0, (size_t)N_NODES * sizeof(int), stream);

    const int eblocks = (N_EDGES + 255) / 256;
    hist_kernel<<<eblocks, 256, 0, stream>>>(head, cnt, N_EDGES);
    scan_part <<<SCAN_NBLK, 256, 0, stream>>>(cnt, bsum, N_NODES);
    scan_bsum <<<1, 512, 0, stream>>>(bsum, SCAN_NBLK);
    scan_final<<<SCAN_NBLK, 256, 0, stream>>>(cnt, bsum, row_ptr, N_NODES);
    fill_kernel<<<eblocks, 256, 0, stream>>>(head, tail, etype, row_ptr, fill, packed, N_EDGES);

    // one wave per node
    const int nthreads = N_NODES * 64;
    const int nblocks  = (nthreads + 255) / 256;
    hop_kernel<true ><<<nblocks, 256, 0, stream>>>(ego, rel, row_ptr, packed, ego, x0, res, N_NODES);
    hop_kernel<false><<<nblocks, 256, 0, stream>>>(x0,  rel, row_ptr, packed, nullptr, x1, res, N_NODES);
    hop_kernel<false><<<nblocks, 256, 0, stream>>>(x1,  rel, row_ptr, packed, nullptr, x0, res, N_NODES);
}

// Round 12
// 234.571 us; speedup vs baseline: 1.1393x; 1.1393x over previous
//
#include <hip/hip_runtime.h>

#define N_NODES 100000
#define N_EDGES 600000
#define EMBED_DIM 128
#define EPSF 1e-12f

#define SCAN_NBLK ((N_NODES + 255) / 256)   // 391
#define N8 (N_NODES * EMBED_DIM / 8)        // 1.6M groups of 8 dims

// ---------------- bf16 helpers (packed ushort pairs in uint32) ----------------
__device__ __forceinline__ float bflo(unsigned u) { return __uint_as_float(u << 16); }
__device__ __forceinline__ float bfhi(unsigned u) { return __uint_as_float(u & 0xFFFF0000u); }
__device__ __forceinline__ unsigned bf16rne(float f) {
    unsigned u = __float_as_uint(f);
    return (u + 0x7FFFu + ((u >> 16) & 1u)) >> 16;   // round-to-nearest-even
}

// ---------------- CSR build ----------------

__global__ void hist_kernel(const int* __restrict__ head, int* __restrict__ cnt, int E) {
    int e = blockIdx.x * blockDim.x + threadIdx.x;
    if (e < E) atomicAdd(&cnt[head[e]], 1);
}

__global__ void scan_part(const int* __restrict__ cnt, int* __restrict__ bsum, int N) {
    __shared__ int lds[256];
    const int t = threadIdx.x;
    const int i = blockIdx.x * 256 + t;
    lds[t] = (i < N) ? cnt[i] : 0;
    __syncthreads();
    for (int off = 128; off; off >>= 1) {
        if (t < off) lds[t] += lds[t + off];
        __syncthreads();
    }
    if (t == 0) bsum[blockIdx.x] = lds[0];
}

__global__ void scan_bsum(int* __restrict__ bsum, int nb) {
    __shared__ int lds[512];
    const int t = threadIdx.x;
    const int v = (t < nb) ? bsum[t] : 0;
    lds[t] = v;
    __syncthreads();
    for (int off = 1; off < 512; off <<= 1) {
        int u = (t >= off) ? lds[t - off] : 0;
        __syncthreads();
        lds[t] += u;
        __syncthreads();
    }
    if (t < nb) bsum[t] = lds[t] - v;   // exclusive
}

__global__ void scan_final(const int* __restrict__ cnt, const int* __restrict__ bsum,
                           int* __restrict__ row_ptr, int N) {
    __shared__ int lds[256];
    const int t = threadIdx.x;
    const int i = blockIdx.x * 256 + t;
    const int v = (i < N) ? cnt[i] : 0;
    lds[t] = v;
    __syncthreads();
    for (int off = 1; off < 256; off <<= 1) {
        int u = (t >= off) ? lds[t - off] : 0;
        __syncthreads();
        lds[t] += u;
        __syncthreads();
    }
    const int excl = lds[t] - v + bsum[blockIdx.x];
    if (i < N) row_ptr[i] = excl;
    if (i == N - 1) row_ptr[N] = excl + v;
}

__global__ void fill_kernel(const int* __restrict__ head, const int* __restrict__ tail,
                            const int* __restrict__ etype, const int* __restrict__ row_ptr,
                            int* __restrict__ fill, int* __restrict__ packed, int E) {
    int e = blockIdx.x * blockDim.x + threadIdx.x;
    if (e < E) {
        int h    = head[e];
        int slot = row_ptr[h] + atomicAdd(&fill[h], 1);
        packed[slot] = tail[e] | (etype[e] << 20);
    }
}

// ---------------- ego fp32 -> bf16 staging ----------------
__global__ void cvt_kernel(const float* __restrict__ in, uint4* __restrict__ out) {
    for (int i = blockIdx.x * blockDim.x + threadIdx.x; i < N8; i += gridDim.x * blockDim.x) {
        const float4 a = ((const float4*)in)[2 * i];
        const float4 b = ((const float4*)in)[2 * i + 1];
        uint4 o;
        o.x = bf16rne(a.x) | (bf16rne(a.y) << 16);
        o.y = bf16rne(a.z) | (bf16rne(a.w) << 16);
        o.z = bf16rne(b.x) | (bf16rne(b.y) << 16);
        o.w = bf16rne(b.z) | (bf16rne(b.w) << 16);
        out[i] = o;
    }
}

// ---------------- fused hop (bf16 state) ----------------
// One wave per node, 4 groups x 16 lanes; group g handles edges g, g+4, ...
// Row = 128 bf16 = 256 B = 16 uint4. Lane p (0..15) owns dims [8p, 8p+8):
// one uint4 (8 bf16) of x, two float4 of rel (fp32, L1-resident).
// Accumulate fp32, normalize fp32, store bf16 (RNE).
// CORRECTNESS: broadcast-loop trip count is WAVE-UNIFORM so every __shfl
// executes full-exec (divergent stride loops around __shfl break for deg>=17:
// ds_bpermute from exec-off lanes returns garbage). Only gather+FMA is
// predicated on e < d0.

__global__ __launch_bounds__(256) void hop_kernel(
    const uint4* __restrict__ xb,   // bf16 rows in
    const float* __restrict__ rel,
    const int* __restrict__ row_ptr, const int* __restrict__ packed,
    uint4* __restrict__ xn, int N) {  // bf16 rows out

    const int wid  = (int)((blockIdx.x * blockDim.x + threadIdx.x) >> 6);
    const int lane = threadIdx.x & 63;
    if (wid >= N) return;

    const int beg = row_ptr[wid];
    const int deg = row_ptr[wid + 1] - beg;

    const int g = lane >> 4;   // edge group (0..3)
    const int p = lane & 15;   // dim slot: owns dims [8p, 8p+8)

    const float4* __restrict__ rel4 = (const float4*)rel;

    const int d0 = min(deg, 64);
    const int pv = (lane < d0) ? packed[beg + lane] : 0;

    float4 accA = make_float4(0.f, 0.f, 0.f, 0.f);
    float4 accB = make_float4(0.f, 0.f, 0.f, 0.f);

    const int niter = (d0 + 3) >> 2;   // wave-uniform trip count
    for (int i = 0; i < niter; ++i) {
        const int e  = g + (i << 2);
        const int pk = __shfl(pv, e, 64);     // full-exec broadcast
        if (e < d0) {
            const int t = pk & 0xFFFFF;
            const int r = pk >> 20;
            const uint4  xv = xb[t * 16 + p];
            const float4 ra = rel4[r * 32 + 2 * p];
            const float4 rb = rel4[r * 32 + 2 * p + 1];
            accA.x = fmaf(bflo(xv.x), ra.x, accA.x);
            accA.y = fmaf(bfhi(xv.x), ra.y, accA.y);
            accA.z = fmaf(bflo(xv.y), ra.z, accA.z);
            accA.w = fmaf(bfhi(xv.y), ra.w, accA.w);
            accB.x = fmaf(bflo(xv.z), rb.x, accB.x);
            accB.y = fmaf(bfhi(xv.z), rb.y, accB.y);
            accB.z = fmaf(bflo(xv.w), rb.z, accB.z);
            accB.w = fmaf(bfhi(xv.w), rb.w, accB.w);
        }
    }
    // rare tail: degree > 64 (direct packed loads, no shfl)
    for (int e = 64 + g; e < deg; e += 4) {
        const int pk = packed[beg + e];
        const int t = pk & 0xFFFFF;
        const int r = pk >> 20;
        const uint4  xv = xb[t * 16 + p];
        const float4 ra = rel4[r * 32 + 2 * p];
        const float4 rb = rel4[r * 32 + 2 * p + 1];
        accA.x = fmaf(bflo(xv.x), ra.x, accA.x);
        accA.y = fmaf(bfhi(xv.x), ra.y, accA.y);
        accA.z = fmaf(bflo(xv.y), ra.z, accA.z);
        accA.w = fmaf(bfhi(xv.y), ra.w, accA.w);
        accB.x = fmaf(bflo(xv.z), rb.x, accB.x);
        accB.y = fmaf(bfhi(xv.z), rb.y, accB.y);
        accB.z = fmaf(bflo(xv.w), rb.z, accB.z);
        accB.w = fmaf(bfhi(xv.w), rb.w, accB.w);
    }

    // fold the 4 edge groups
    accA.x += __shfl_xor(accA.x, 16, 64); accA.x += __shfl_xor(accA.x, 32, 64);
    accA.y += __shfl_xor(accA.y, 16, 64); accA.y += __shfl_xor(accA.y, 32, 64);
    accA.z += __shfl_xor(accA.z, 16, 64); accA.z += __shfl_xor(accA.z, 32, 64);
    accA.w += __shfl_xor(accA.w, 16, 64); accA.w += __shfl_xor(accA.w, 32, 64);
    accB.x += __shfl_xor(accB.x, 16, 64); accB.x += __shfl_xor(accB.x, 32, 64);
    accB.y += __shfl_xor(accB.y, 16, 64); accB.y += __shfl_xor(accB.y, 32, 64);
    accB.z += __shfl_xor(accB.z, 16, 64); accB.z += __shfl_xor(accB.z, 32, 64);
    accB.w += __shfl_xor(accB.w, 16, 64); accB.w += __shfl_xor(accB.w, 32, 64);

    const float inv = 1.0f / (float)max(deg, 1);
    accA.x *= inv; accA.y *= inv; accA.z *= inv; accA.w *= inv;
    accB.x *= inv; accB.y *= inv; accB.z *= inv; accB.w *= inv;

    // sum of squares: 8 local dims, fold across the 16 dim slots
    float ss = accA.x * accA.x + accA.y * accA.y + accA.z * accA.z + accA.w * accA.w
             + accB.x * accB.x + accB.y * accB.y + accB.z * accB.z + accB.w * accB.w;
    #pragma unroll
    for (int off = 8; off; off >>= 1) ss += __shfl_xor(ss, off, 64);

    const float scale = 1.0f / fmaxf(sqrtf(ss), EPSF);

    if (g == 0) {
        const float v0 = accA.x * scale, v1 = accA.y * scale;
        const float v2 = accA.z * scale, v3 = accA.w * scale;
        const float v4 = accB.x * scale, v5 = accB.y * scale;
        const float v6 = accB.z * scale, v7 = accB.w * scale;
        uint4 o;
        o.x = bf16rne(v0) | (bf16rne(v1) << 16);
        o.y = bf16rne(v2) | (bf16rne(v3) << 16);
        o.z = bf16rne(v4) | (bf16rne(v5) << 16);
        o.w = bf16rne(v6) | (bf16rne(v7) << 16);
        xn[wid * 16 + p] = o;
    }
}

// ---------------- final: res = ego + x1 + x2 + x3 ----------------
__global__ void final_kernel(const float* __restrict__ ego,
                             const uint4* __restrict__ x1,
                             const uint4* __restrict__ x2,
                             const uint4* __restrict__ x3,
                             float* __restrict__ res) {
    for (int i = blockIdx.x * blockDim.x + threadIdx.x; i < N8; i += gridDim.x * blockDim.x) {
        float4 a = ((const float4*)ego)[2 * i];
        float4 b = ((const float4*)ego)[2 * i + 1];
        const uint4 u1 = x1[i], u2 = x2[i], u3 = x3[i];
        a.x += bflo(u1.x) + bflo(u2.x) + bflo(u3.x);
        a.y += bfhi(u1.x) + bfhi(u2.x) + bfhi(u3.x);
        a.z += bflo(u1.y) + bflo(u2.y) + bflo(u3.y);
        a.w += bfhi(u1.y) + bfhi(u2.y) + bfhi(u3.y);
        b.x += bflo(u1.z) + bflo(u2.z) + bflo(u3.z);
        b.y += bfhi(u1.z) + bfhi(u2.z) + bfhi(u3.z);
        b.z += bflo(u1.w) + bflo(u2.w) + bflo(u3.w);
        b.w += bfhi(u1.w) + bfhi(u2.w) + bfhi(u3.w);
        ((float4*)res)[2 * i]     = a;
        ((float4*)res)[2 * i + 1] = b;
    }
}

// ---------------- launch ----------------

extern "C" void kernel_launch(void* const* d_in, const int* in_sizes, int n_in,
                              void* d_out, int out_size, void* d_ws, size_t ws_size,
                              hipStream_t stream) {
    const float* ego   = (const float*)d_in[0];
    const int*   eidx  = (const int*)d_in[1];   // [2, E]: row 0 = head, row 1 = tail
    const int*   etype = (const int*)d_in[2];
    const float* rel   = (const float*)d_in[3];
    // d_in[4] = dropout scalar (0 in eval) -> ignored

    const int* head = eidx;
    const int* tail = eidx + N_EDGES;
    float* res = (float*)d_out;

    // workspace layout
    char* ws = (char*)d_ws;
    int* cnt     = (int*)ws;  ws += (size_t)N_NODES * sizeof(int);
    int* row_ptr = (int*)ws;  ws += (size_t)(N_NODES + 1) * sizeof(int);
    int* fill    = (int*)ws;  ws += (size_t)N_NODES * sizeof(int);
    int* packed  = (int*)ws;  ws += (size_t)N_EDGES * sizeof(int);
    int* bsum    = (int*)ws;  ws += (size_t)SCAN_NBLK * sizeof(int);
    ws = (char*)(((uintptr_t)ws + 255) & ~(uintptr_t)255);
    const size_t xbytes = (size_t)N_NODES * EMBED_DIM * 2;   // bf16
    uint4* egob = (uint4*)ws;  ws += xbytes;
    uint4* xb1  = (uint4*)ws;  ws += xbytes;
    uint4* xb2  = (uint4*)ws;  ws += xbytes;
    uint4* xb3  = (uint4*)ws;

    hipMemsetAsync(cnt,  0, (size_t)N_NODES * sizeof(int), stream);
    hipMemsetAsync(fill, 0, (size_t)N_NODES * sizeof(int), stream);

    const int eblocks = (N_EDGES + 255) / 256;
    cvt_kernel<<<2048, 256, 0, stream>>>(ego, egob);
    hist_kernel<<<eblocks, 256, 0, stream>>>(head, cnt, N_EDGES);
    scan_part <<<SCAN_NBLK, 256, 0, stream>>>(cnt, bsum, N_NODES);
    scan_bsum <<<1, 512, 0, stream>>>(bsum, SCAN_NBLK);
    scan_final<<<SCAN_NBLK, 256, 0, stream>>>(cnt, bsum, row_ptr, N_NODES);
    fill_kernel<<<eblocks, 256, 0, stream>>>(head, tail, etype, row_ptr, fill, packed, N_EDGES);

    // one wave per node
    const int nblocks = (N_NODES * 64 + 255) / 256;
    hop_kernel<<<nblocks, 256, 0, stream>>>(egob, rel, row_ptr, packed, xb1, N_NODES);
    hop_kernel<<<nblocks, 256, 0, stream>>>(xb1,  rel, row_ptr, packed, xb2, N_NODES);
    hop_kernel<<<nblocks, 256, 0, stream>>>(xb2,  rel, row_ptr, packed, xb3, N_NODES);

    final_kernel<<<2048, 256, 0, stream>>>(ego, xb1, xb2, xb3, res);
}

// Round 13
// 203.814 us; speedup vs baseline: 1.3112x; 1.1509x over previous
//
#include <hip/hip_runtime.h>

#define N_NODES 100000
#define N_EDGES 600000
#define EMBED_DIM 128
#define EPSF 1e-12f

#define SCAN_NBLK ((N_NODES + 255) / 256)   // 391
#define N8 (N_NODES * EMBED_DIM / 8)        // 1.6M groups of 8 dims

// ---------------- bf16 helpers (packed ushort pairs in uint32) ----------------
__device__ __forceinline__ float bflo(unsigned u) { return __uint_as_float(u << 16); }
__device__ __forceinline__ float bfhi(unsigned u) { return __uint_as_float(u & 0xFFFF0000u); }
__device__ __forceinline__ unsigned bf16rne(float f) {
    unsigned u = __float_as_uint(f);
    return (u + 0x7FFFu + ((u >> 16) & 1u)) >> 16;   // round-to-nearest-even
}

// ---------------- CSR build ----------------

__global__ void hist_kernel(const int* __restrict__ head, int* __restrict__ cnt, int E) {
    int e = blockIdx.x * blockDim.x + threadIdx.x;
    if (e < E) atomicAdd(&cnt[head[e]], 1);
}

__global__ void scan_part(const int* __restrict__ cnt, int* __restrict__ bsum, int N) {
    __shared__ int lds[256];
    const int t = threadIdx.x;
    const int i = blockIdx.x * 256 + t;
    lds[t] = (i < N) ? cnt[i] : 0;
    __syncthreads();
    for (int off = 128; off; off >>= 1) {
        if (t < off) lds[t] += lds[t + off];
        __syncthreads();
    }
    if (t == 0) bsum[blockIdx.x] = lds[0];
}

__global__ void scan_bsum(int* __restrict__ bsum, int nb) {
    __shared__ int lds[512];
    const int t = threadIdx.x;
    const int v = (t < nb) ? bsum[t] : 0;
    lds[t] = v;
    __syncthreads();
    for (int off = 1; off < 512; off <<= 1) {
        int u = (t >= off) ? lds[t - off] : 0;
        __syncthreads();
        lds[t] += u;
        __syncthreads();
    }
    if (t < nb) bsum[t] = lds[t] - v;   // exclusive
}

__global__ void scan_final(const int* __restrict__ cnt, const int* __restrict__ bsum,
                           int* __restrict__ row_ptr, int N) {
    __shared__ int lds[256];
    const int t = threadIdx.x;
    const int i = blockIdx.x * 256 + t;
    const int v = (i < N) ? cnt[i] : 0;
    lds[t] = v;
    __syncthreads();
    for (int off = 1; off < 256; off <<= 1) {
        int u = (t >= off) ? lds[t - off] : 0;
        __syncthreads();
        lds[t] += u;
        __syncthreads();
    }
    const int excl = lds[t] - v + bsum[blockIdx.x];
    if (i < N) row_ptr[i] = excl;
    if (i == N - 1) row_ptr[N] = excl + v;
}

__global__ void fill_kernel(const int* __restrict__ head, const int* __restrict__ tail,
                            const int* __restrict__ etype, const int* __restrict__ row_ptr,
                            int* __restrict__ fill, int* __restrict__ packed, int E) {
    int e = blockIdx.x * blockDim.x + threadIdx.x;
    if (e < E) {
        int h    = head[e];
        int slot = row_ptr[h] + atomicAdd(&fill[h], 1);
        packed[slot] = tail[e] | (etype[e] << 20);
    }
}

// ---------------- ego fp32 -> bf16 staging ----------------
__global__ void cvt_kernel(const float* __restrict__ in, uint4* __restrict__ out) {
    for (int i = blockIdx.x * blockDim.x + threadIdx.x; i < N8; i += gridDim.x * blockDim.x) {
        const float4 a = ((const float4*)in)[2 * i];
        const float4 b = ((const float4*)in)[2 * i + 1];
        uint4 o;
        o.x = bf16rne(a.x) | (bf16rne(a.y) << 16);
        o.y = bf16rne(a.z) | (bf16rne(a.w) << 16);
        o.z = bf16rne(b.x) | (bf16rne(b.y) << 16);
        o.w = bf16rne(b.z) | (bf16rne(b.w) << 16);
        out[i] = o;
    }
}

// ---------------- fused hop (bf16 state, group-per-node) ----------------
// 4 nodes per wave: each 16-lane group owns ONE node and walks all its edges
// serially (the wave's 4 groups run 4 independent row-gathers in parallel).
// Lane p (0..15) of a group owns dims [8p, 8p+8): one uint4 (8 bf16) of x,
// two float4 of rel (fp32, L1-resident). Accumulate fp32 -> each lane already
// holds the full edge-sum for its dims: NO cross-group fold needed. ss-fold is
// 4 shfl_xor within the group. All 64 lanes store (4 rows / wave, contiguous).
//
// SHFL SAFETY: broadcasts source only lanes of the SAME group (gbase + e).
// While a group iterates, its 16 lanes are all active (trip count is
// group-uniform), so ds_bpermute never sources an exec-off lane. (Sourcing
// other groups' lanes after they exited is what broke R9/R10.)

__global__ __launch_bounds__(256) void hop_kernel(
    const uint4* __restrict__ xb,   // bf16 rows in
    const float* __restrict__ rel,
    const int* __restrict__ row_ptr, const int* __restrict__ packed,
    uint4* __restrict__ xn, int N) {  // bf16 rows out

    const int lane = threadIdx.x & 63;
    const int wave = (int)((blockIdx.x * blockDim.x + threadIdx.x) >> 6);
    const int g = lane >> 4;          // group (0..3)
    const int p = lane & 15;          // dim slot: owns dims [8p, 8p+8)
    const int wid = wave * 4 + g;     // node id (uniform within group)
    if (wid >= N) return;

    const int beg = row_ptr[wid];
    const int deg = row_ptr[wid + 1] - beg;

    const float4* __restrict__ rel4 = (const float4*)rel;

    // preload up to 16 packed entries, one per group lane
    const int d0 = min(deg, 16);
    const int pv = (p < d0) ? packed[beg + p] : 0;
    const int gbase = lane & 48;      // g*16

    float4 accA = make_float4(0.f, 0.f, 0.f, 0.f);
    float4 accB = make_float4(0.f, 0.f, 0.f, 0.f);

    for (int e = 0; e < d0; ++e) {            // group-uniform trip count
        const int pk = __shfl(pv, gbase + e, 64);   // in-group broadcast
        const int t = pk & 0xFFFFF;
        const int r = pk >> 20;
        const uint4  xv = xb[t * 16 + p];
        const float4 ra = rel4[r * 32 + 2 * p];
        const float4 rb = rel4[r * 32 + 2 * p + 1];
        accA.x = fmaf(bflo(xv.x), ra.x, accA.x);
        accA.y = fmaf(bfhi(xv.x), ra.y, accA.y);
        accA.z = fmaf(bflo(xv.y), ra.z, accA.z);
        accA.w = fmaf(bfhi(xv.y), ra.w, accA.w);
        accB.x = fmaf(bflo(xv.z), rb.x, accB.x);
        accB.y = fmaf(bfhi(xv.z), rb.y, accB.y);
        accB.z = fmaf(bflo(xv.w), rb.z, accB.z);
        accB.w = fmaf(bfhi(xv.w), rb.w, accB.w);
    }
    // rare tail: degree > 16 (direct packed loads; same addr across the group -> L1 broadcast)
    for (int e = 16; e < deg; ++e) {
        const int pk = packed[beg + e];
        const int t = pk & 0xFFFFF;
        const int r = pk >> 20;
        const uint4  xv = xb[t * 16 + p];
        const float4 ra = rel4[r * 32 + 2 * p];
        const float4 rb = rel4[r * 32 + 2 * p + 1];
        accA.x = fmaf(bflo(xv.x), ra.x, accA.x);
        accA.y = fmaf(bfhi(xv.x), ra.y, accA.y);
        accA.z = fmaf(bflo(xv.y), ra.z, accA.z);
        accA.w = fmaf(bfhi(xv.y), ra.w, accA.w);
        accB.x = fmaf(bflo(xv.z), rb.x, accB.x);
        accB.y = fmaf(bfhi(xv.z), rb.y, accB.y);
        accB.z = fmaf(bflo(xv.w), rb.z, accB.z);
        accB.w = fmaf(bfhi(xv.w), rb.w, accB.w);
    }

    const float inv = 1.0f / (float)max(deg, 1);
    accA.x *= inv; accA.y *= inv; accA.z *= inv; accA.w *= inv;
    accB.x *= inv; accB.y *= inv; accB.z *= inv; accB.w *= inv;

    // sum of squares: 8 local dims, fold across the 16 group lanes
    float ss = accA.x * accA.x + accA.y * accA.y + accA.z * accA.z + accA.w * accA.w
             + accB.x * accB.x + accB.y * accB.y + accB.z * accB.z + accB.w * accB.w;
    #pragma unroll
    for (int off = 8; off; off >>= 1) ss += __shfl_xor(ss, off, 64);  // in-group

    const float scale = 1.0f / fmaxf(sqrtf(ss), EPSF);

    uint4 o;
    o.x = bf16rne(accA.x * scale) | (bf16rne(accA.y * scale) << 16);
    o.y = bf16rne(accA.z * scale) | (bf16rne(accA.w * scale) << 16);
    o.z = bf16rne(accB.x * scale) | (bf16rne(accB.y * scale) << 16);
    o.w = bf16rne(accB.z * scale) | (bf16rne(accB.w * scale) << 16);
    xn[wid * 16 + p] = o;   // full-wave store: 4 contiguous rows per wave
}

// ---------------- final: res = ego + x1 + x2 + x3 ----------------
__global__ void final_kernel(const float* __restrict__ ego,
                             const uint4* __restrict__ x1,
                             const uint4* __restrict__ x2,
                             const uint4* __restrict__ x3,
                             float* __restrict__ res) {
    for (int i = blockIdx.x * blockDim.x + threadIdx.x; i < N8; i += gridDim.x * blockDim.x) {
        float4 a = ((const float4*)ego)[2 * i];
        float4 b = ((const float4*)ego)[2 * i + 1];
        const uint4 u1 = x1[i], u2 = x2[i], u3 = x3[i];
        a.x += bflo(u1.x) + bflo(u2.x) + bflo(u3.x);
        a.y += bfhi(u1.x) + bfhi(u2.x) + bfhi(u3.x);
        a.z += bflo(u1.y) + bflo(u2.y) + bflo(u3.y);
        a.w += bfhi(u1.y) + bfhi(u2.y) + bfhi(u3.y);
        b.x += bflo(u1.z) + bflo(u2.z) + bflo(u3.z);
        b.y += bfhi(u1.z) + bfhi(u2.z) + bfhi(u3.z);
        b.z += bflo(u1.w) + bflo(u2.w) + bflo(u3.w);
        b.w += bfhi(u1.w) + bfhi(u2.w) + bfhi(u3.w);
        ((float4*)res)[2 * i]     = a;
        ((float4*)res)[2 * i + 1] = b;
    }
}

// ---------------- launch ----------------

extern "C" void kernel_launch(void* const* d_in, const int* in_sizes, int n_in,
                              void* d_out, int out_size, void* d_ws, size_t ws_size,
                              hipStream_t stream) {
    const float* ego   = (const float*)d_in[0];
    const int*   eidx  = (const int*)d_in[1];   // [2, E]: row 0 = head, row 1 = tail
    const int*   etype = (const int*)d_in[2];
    const float* rel   = (const float*)d_in[3];
    // d_in[4] = dropout scalar (0 in eval) -> ignored

    const int* head = eidx;
    const int* tail = eidx + N_EDGES;
    float* res = (float*)d_out;

    // workspace layout
    char* ws = (char*)d_ws;
    int* cnt     = (int*)ws;  ws += (size_t)N_NODES * sizeof(int);
    int* row_ptr = (int*)ws;  ws += (size_t)(N_NODES + 1) * sizeof(int);
    int* fill    = (int*)ws;  ws += (size_t)N_NODES * sizeof(int);
    int* packed  = (int*)ws;  ws += (size_t)N_EDGES * sizeof(int);
    int* bsum    = (int*)ws;  ws += (size_t)SCAN_NBLK * sizeof(int);
    ws = (char*)(((uintptr_t)ws + 255) & ~(uintptr_t)255);
    const size_t xbytes = (size_t)N_NODES * EMBED_DIM * 2;   // bf16
    uint4* egob = (uint4*)ws;  ws += xbytes;
    uint4* xb1  = (uint4*)ws;  ws += xbytes;
    uint4* xb2  = (uint4*)ws;  ws += xbytes;
    uint4* xb3  = (uint4*)ws;

    hipMemsetAsync(cnt,  0, (size_t)N_NODES * sizeof(int), stream);
    hipMemsetAsync(fill, 0, (size_t)N_NODES * sizeof(int), stream);

    const int eblocks = (N_EDGES + 255) / 256;
    cvt_kernel<<<2048, 256, 0, stream>>>(ego, egob);
    hist_kernel<<<eblocks, 256, 0, stream>>>(head, cnt, N_EDGES);
    scan_part <<<SCAN_NBLK, 256, 0, stream>>>(cnt, bsum, N_NODES);
    scan_bsum <<<1, 512, 0, stream>>>(bsum, SCAN_NBLK);
    scan_final<<<SCAN_NBLK, 256, 0, stream>>>(cnt, bsum, row_ptr, N_NODES);
    fill_kernel<<<eblocks, 256, 0, stream>>>(head, tail, etype, row_ptr, fill, packed, N_EDGES);

    // 4 nodes per wave -> 16 nodes per 256-thread block
    const int nblocks = (N_NODES + 15) / 16;
    hop_kernel<<<nblocks, 256, 0, stream>>>(egob, rel, row_ptr, packed, xb1, N_NODES);
    hop_kernel<<<nblocks, 256, 0, stream>>>(xb1,  rel, row_ptr, packed, xb2, N_NODES);
    hop_kernel<<<nblocks, 256, 0, stream>>>(xb2,  rel, row_ptr, packed, xb3, N_NODES);

    final_kernel<<<2048, 256, 0, stream>>>(ego, xb1, xb2, xb3, res);
}

// Round 14
// 188.554 us; speedup vs baseline: 1.4173x; 1.0809x over previous
//
#include <hip/hip_runtime.h>

#define N_NODES 100000
#define N_EDGES 600000
#define EMBED_DIM 128
#define EPSF 1e-12f

#define SCAN_NBLK ((N_NODES + 255) / 256)   // 391
#define N8 (N_NODES * EMBED_DIM / 8)        // 1.6M groups of 8 dims
#define EQ4 (N_EDGES / 4)                   // 150000

// ---------------- bf16 helpers (packed ushort pairs in uint32) ----------------
__device__ __forceinline__ float bflo(unsigned u) { return __uint_as_float(u << 16); }
__device__ __forceinline__ float bfhi(unsigned u) { return __uint_as_float(u & 0xFFFF0000u); }
__device__ __forceinline__ unsigned bf16rne(float f) {
    unsigned u = __float_as_uint(f);
    return (u + 0x7FFFu + ((u >> 16) & 1u)) >> 16;   // round-to-nearest-even
}

// ---------------- zero cnt ----------------
__global__ void zero_kernel(uint4* __restrict__ p, int n4) {
    int i = blockIdx.x * blockDim.x + threadIdx.x;
    if (i < n4) p[i] = make_uint4(0, 0, 0, 0);
}

// ---------------- CSR build ----------------

// 4 edges per thread (stride EQ4), fire-and-forget atomics
__global__ void hist_kernel(const int* __restrict__ head, int* __restrict__ cnt) {
    const int tid = blockIdx.x * blockDim.x + threadIdx.x;
    if (tid < EQ4) {
        atomicAdd(&cnt[head[tid]], 1);
        atomicAdd(&cnt[head[tid + EQ4]], 1);
        atomicAdd(&cnt[head[tid + 2 * EQ4]], 1);
        atomicAdd(&cnt[head[tid + 3 * EQ4]], 1);
    }
}

__global__ void scan_part(const int* __restrict__ cnt, int* __restrict__ bsum, int N) {
    __shared__ int lds[256];
    const int t = threadIdx.x;
    const int i = blockIdx.x * 256 + t;
    lds[t] = (i < N) ? cnt[i] : 0;
    __syncthreads();
    for (int off = 128; off; off >>= 1) {
        if (t < off) lds[t] += lds[t + off];
        __syncthreads();
    }
    if (t == 0) bsum[blockIdx.x] = lds[0];
}

__global__ void scan_bsum(int* __restrict__ bsum, int nb) {
    __shared__ int lds[512];
    const int t = threadIdx.x;
    const int v = (t < nb) ? bsum[t] : 0;
    lds[t] = v;
    __syncthreads();
    for (int off = 1; off < 512; off <<= 1) {
        int u = (t >= off) ? lds[t - off] : 0;
        __syncthreads();
        lds[t] += u;
        __syncthreads();
    }
    if (t < nb) bsum[t] = lds[t] - v;   // exclusive
}

// writes row_ptr AND next (the atomic fill cursor, preloaded with row starts)
__global__ void scan_final(const int* __restrict__ cnt, const int* __restrict__ bsum,
                           int* __restrict__ row_ptr, int* __restrict__ next, int N) {
    __shared__ int lds[256];
    const int t = threadIdx.x;
    const int i = blockIdx.x * 256 + t;
    const int v = (i < N) ? cnt[i] : 0;
    lds[t] = v;
    __syncthreads();
    for (int off = 1; off < 256; off <<= 1) {
        int u = (t >= off) ? lds[t - off] : 0;
        __syncthreads();
        lds[t] += u;
        __syncthreads();
    }
    const int excl = lds[t] - v + bsum[blockIdx.x];
    if (i < N) { row_ptr[i] = excl; next[i] = excl; }
    if (i == N - 1) row_ptr[N] = excl + v;
}

// 4 edges per thread; atomicAdd(&next[h],1) yields the slot directly.
__global__ void fill_kernel(const int* __restrict__ head, const int* __restrict__ tail,
                            const int* __restrict__ etype, int* __restrict__ next,
                            int* __restrict__ packed) {
    const int tid = blockIdx.x * blockDim.x + threadIdx.x;
    if (tid >= EQ4) return;
    const int e0 = tid, e1 = tid + EQ4, e2 = tid + 2 * EQ4, e3 = tid + 3 * EQ4;
    const int h0 = head[e0], h1 = head[e1], h2 = head[e2], h3 = head[e3];
    const int p0 = tail[e0] | (etype[e0] << 20);
    const int p1 = tail[e1] | (etype[e1] << 20);
    const int p2 = tail[e2] | (etype[e2] << 20);
    const int p3 = tail[e3] | (etype[e3] << 20);
    const int s0 = atomicAdd(&next[h0], 1);
    const int s1 = atomicAdd(&next[h1], 1);
    const int s2 = atomicAdd(&next[h2], 1);
    const int s3 = atomicAdd(&next[h3], 1);
    packed[s0] = p0;
    packed[s1] = p1;
    packed[s2] = p2;
    packed[s3] = p3;
}

// ---------------- ego fp32 -> bf16 staging ----------------
__global__ void cvt_kernel(const float* __restrict__ in, uint4* __restrict__ out) {
    for (int i = blockIdx.x * blockDim.x + threadIdx.x; i < N8; i += gridDim.x * blockDim.x) {
        const float4 a = ((const float4*)in)[2 * i];
        const float4 b = ((const float4*)in)[2 * i + 1];
        uint4 o;
        o.x = bf16rne(a.x) | (bf16rne(a.y) << 16);
        o.y = bf16rne(a.z) | (bf16rne(a.w) << 16);
        o.z = bf16rne(b.x) | (bf16rne(b.y) << 16);
        o.w = bf16rne(b.z) | (bf16rne(b.w) << 16);
        out[i] = o;
    }
}

// ---------------- fused hop (bf16 state, group-per-node) ----------------
// 4 nodes per wave: each 16-lane group owns ONE node, walks all its edges.
// Lane p (0..15) owns dims [8p, 8p+8). Accumulate fp32; each lane holds the
// full edge-sum for its dims (no cross-group fold). ss-fold = 4 in-group
// shfl_xor. All 64 lanes store.
// SHFL SAFETY: broadcasts source only SAME-group lanes; trip count is
// group-uniform, so ds_bpermute never sources an exec-off lane.

#define HOP_GATHER_BODY                                                        \
    const int lane = threadIdx.x & 63;                                         \
    const int wave = (int)((blockIdx.x * blockDim.x + threadIdx.x) >> 6);      \
    const int g = lane >> 4;                                                   \
    const int p = lane & 15;                                                   \
    const int wid = wave * 4 + g;                                              \
    if (wid >= N) return;                                                      \
    const int beg = row_ptr[wid];                                              \
    const int deg = row_ptr[wid + 1] - beg;                                    \
    const float4* __restrict__ rel4 = (const float4*)rel;                      \
    const int d0 = min(deg, 16);                                               \
    const int pv = (p < d0) ? packed[beg + p] : 0;                             \
    const int gbase = lane & 48;                                               \
    float4 accA = make_float4(0.f, 0.f, 0.f, 0.f);                             \
    float4 accB = make_float4(0.f, 0.f, 0.f, 0.f);                             \
    for (int e = 0; e < d0; ++e) {                                             \
        const int pk = __shfl(pv, gbase + e, 64);                              \
        const int t = pk & 0xFFFFF;                                            \
        const int r = pk >> 20;                                                \
        const uint4  xv = xb[t * 16 + p];                                      \
        const float4 ra = rel4[r * 32 + 2 * p];                                \
        const float4 rb = rel4[r * 32 + 2 * p + 1];                            \
        accA.x = fmaf(bflo(xv.x), ra.x, accA.x);                               \
        accA.y = fmaf(bfhi(xv.x), ra.y, accA.y);                               \
        accA.z = fmaf(bflo(xv.y), ra.z, accA.z);                               \
        accA.w = fmaf(bfhi(xv.y), ra.w, accA.w);                               \
        accB.x = fmaf(bflo(xv.z), rb.x, accB.x);                               \
        accB.y = fmaf(bfhi(xv.z), rb.y, accB.y);                               \
        accB.z = fmaf(bflo(xv.w), rb.z, accB.z);                               \
        accB.w = fmaf(bfhi(xv.w), rb.w, accB.w);                               \
    }                                                                          \
    for (int e = 16; e < deg; ++e) {                                           \
        const int pk = packed[beg + e];                                        \
        const int t = pk & 0xFFFFF;                                            \
        const int r = pk >> 20;                                                \
        const uint4  xv = xb[t * 16 + p];                                      \
        const float4 ra = rel4[r * 32 + 2 * p];                                \
        const float4 rb = rel4[r * 32 + 2 * p + 1];                            \
        accA.x = fmaf(bflo(xv.x), ra.x, accA.x);                               \
        accA.y = fmaf(bfhi(xv.x), ra.y, accA.y);                               \
        accA.z = fmaf(bflo(xv.y), ra.z, accA.z);                               \
        accA.w = fmaf(bfhi(xv.y), ra.w, accA.w);                               \
        accB.x = fmaf(bflo(xv.z), rb.x, accB.x);                               \
        accB.y = fmaf(bfhi(xv.z), rb.y, accB.y);                               \
        accB.z = fmaf(bflo(xv.w), rb.z, accB.z);                               \
        accB.w = fmaf(bfhi(xv.w), rb.w, accB.w);                               \
    }                                                                          \
    const float inv = 1.0f / (float)max(deg, 1);                               \
    accA.x *= inv; accA.y *= inv; accA.z *= inv; accA.w *= inv;                \
    accB.x *= inv; accB.y *= inv; accB.z *= inv; accB.w *= inv;                \
    float ss = accA.x * accA.x + accA.y * accA.y + accA.z * accA.z             \
             + accA.w * accA.w + accB.x * accB.x + accB.y * accB.y             \
             + accB.z * accB.z + accB.w * accB.w;                              \
    _Pragma("unroll")                                                          \
    for (int off = 8; off; off >>= 1) ss += __shfl_xor(ss, off, 64);           \
    const float scale = 1.0f / fmaxf(sqrtf(ss), EPSF);

__global__ __launch_bounds__(256) void hop_kernel(
    const uint4* __restrict__ xb, const float* __restrict__ rel,
    const int* __restrict__ row_ptr, const int* __restrict__ packed,
    uint4* __restrict__ xn, int N) {

    HOP_GATHER_BODY

    uint4 o;
    o.x = bf16rne(accA.x * scale) | (bf16rne(accA.y * scale) << 16);
    o.y = bf16rne(accA.z * scale) | (bf16rne(accA.w * scale) << 16);
    o.z = bf16rne(accB.x * scale) | (bf16rne(accB.y * scale) << 16);
    o.w = bf16rne(accB.z * scale) | (bf16rne(accB.w * scale) << 16);
    xn[wid * 16 + p] = o;
}

// hop 3 fused with the residual sum: res = ego + x1 + x2 + x3 (fp32 out)
__global__ __launch_bounds__(256) void hop_final_kernel(
    const uint4* __restrict__ xb, const float* __restrict__ rel,
    const int* __restrict__ row_ptr, const int* __restrict__ packed,
    const float* __restrict__ ego, const uint4* __restrict__ x1,
    const uint4* __restrict__ x2, float* __restrict__ res, int N) {

    HOP_GATHER_BODY

    const float4 e0 = ((const float4*)ego)[wid * 32 + 2 * p];
    const float4 e1 = ((const float4*)ego)[wid * 32 + 2 * p + 1];
    const uint4 u1 = x1[wid * 16 + p];
    const uint4 u2 = x2[wid * 16 + p];
    float4 o0, o1;
    o0.x = e0.x + bflo(u1.x) + bflo(u2.x) + accA.x * scale;
    o0.y = e0.y + bfhi(u1.x) + bfhi(u2.x) + accA.y * scale;
    o0.z = e0.z + bflo(u1.y) + bflo(u2.y) + accA.z * scale;
    o0.w = e0.w + bfhi(u1.y) + bfhi(u2.y) + accA.w * scale;
    o1.x = e1.x + bflo(u1.z) + bflo(u2.z) + accB.x * scale;
    o1.y = e1.y + bfhi(u1.z) + bfhi(u2.z) + accB.y * scale;
    o1.z = e1.z + bflo(u1.w) + bflo(u2.w) + accB.z * scale;
    o1.w = e1.w + bfhi(u1.w) + bfhi(u2.w) + accB.w * scale;
    ((float4*)res)[wid * 32 + 2 * p]     = o0;
    ((float4*)res)[wid * 32 + 2 * p + 1] = o1;
}

// ---------------- launch ----------------

extern "C" void kernel_launch(void* const* d_in, const int* in_sizes, int n_in,
                              void* d_out, int out_size, void* d_ws, size_t ws_size,
                              hipStream_t stream) {
    const float* ego   = (const float*)d_in[0];
    const int*   eidx  = (const int*)d_in[1];   // [2, E]: row 0 = head, row 1 = tail
    const int*   etype = (const int*)d_in[2];
    const float* rel   = (const float*)d_in[3];
    // d_in[4] = dropout scalar (0 in eval) -> ignored

    const int* head = eidx;
    const int* tail = eidx + N_EDGES;
    float* res = (float*)d_out;

    // workspace layout
    char* ws = (char*)d_ws;
    int* cnt     = (int*)ws;  ws += (size_t)N_NODES * sizeof(int);
    int* row_ptr = (int*)ws;  ws += (size_t)(N_NODES + 1) * sizeof(int);
    int* next    = (int*)ws;  ws += (size_t)N_NODES * sizeof(int);
    int* packed  = (int*)ws;  ws += (size_t)N_EDGES * sizeof(int);
    int* bsum    = (int*)ws;  ws += (size_t)SCAN_NBLK * sizeof(int);
    ws = (char*)(((uintptr_t)ws + 255) & ~(uintptr_t)255);
    const size_t xbytes = (size_t)N_NODES * EMBED_DIM * 2;   // bf16
    uint4* egob = (uint4*)ws;  ws += xbytes;
    uint4* xb1  = (uint4*)ws;  ws += xbytes;
    uint4* xb2  = (uint4*)ws;

    const int n4cnt = (N_NODES * 4 + 15) / 16;   // uint4 count for cnt
    zero_kernel<<<(n4cnt + 255) / 256, 256, 0, stream>>>((uint4*)cnt, n4cnt);
    cvt_kernel<<<2048, 256, 0, stream>>>(ego, egob);

    const int e4blocks = (EQ4 + 255) / 256;
    hist_kernel<<<e4blocks, 256, 0, stream>>>(head, cnt);
    scan_part <<<SCAN_NBLK, 256, 0, stream>>>(cnt, bsum, N_NODES);
    scan_bsum <<<1, 512, 0, stream>>>(bsum, SCAN_NBLK);
    scan_final<<<SCAN_NBLK, 256, 0, stream>>>(cnt, bsum, row_ptr, next, N_NODES);
    fill_kernel<<<e4blocks, 256, 0, stream>>>(head, tail, etype, next, packed);

    // 4 nodes per wave -> 16 nodes per 256-thread block
    const int nblocks = (N_NODES + 15) / 16;
    hop_kernel<<<nblocks, 256, 0, stream>>>(egob, rel, row_ptr, packed, xb1, N_NODES);
    hop_kernel<<<nblocks, 256, 0, stream>>>(xb1,  rel, row_ptr, packed, xb2, N_NODES);
    hop_final_kernel<<<nblocks, 256, 0, stream>>>(xb2, rel, row_ptr, packed,
                                                  ego, xb1, xb2, res, N_NODES);
}

// Round 15
// 180.437 us; speedup vs baseline: 1.4811x; 1.0450x over previous
//
#include <hip/hip_runtime.h>

#define N_NODES 100000
#define N_EDGES 600000
#define EMBED_DIM 128
#define EPSF 1e-12f

#define SCAN_NBLK ((N_NODES + 255) / 256)   // 391
#define N8 (N_NODES * EMBED_DIM / 8)        // 1.6M groups of 8 dims
#define EQ4 (N_EDGES / 4)                   // 150000
#define EQ8 (N_EDGES / 8)                   // 75000
#define HIST_BLOCKS 600                     // ceil(EQ4/256) = 586 -> 600
#define CVT_BLOCKS 1448

// ---------------- bf16 helpers (packed ushort pairs in uint32) ----------------
__device__ __forceinline__ float bflo(unsigned u) { return __uint_as_float(u << 16); }
__device__ __forceinline__ float bfhi(unsigned u) { return __uint_as_float(u & 0xFFFF0000u); }
__device__ __forceinline__ unsigned bf16rne(float f) {
    unsigned u = __float_as_uint(f);
    return (u + 0x7FFFu + ((u >> 16) & 1u)) >> 16;   // round-to-nearest-even
}

// ---------------- zero cnt ----------------
__global__ void zero_kernel(uint4* __restrict__ p, int n4) {
    int i = blockIdx.x * blockDim.x + threadIdx.x;
    if (i < n4) p[i] = make_uint4(0, 0, 0, 0);
}

// ---------------- fused: ego->bf16 cvt  ||  head histogram ----------------
// Blocks [0, HIST_BLOCKS): 4 fire-and-forget atomics per thread.
// Blocks [HIST_BLOCKS, HIST_BLOCKS+CVT_BLOCKS): grid-stride bf16 convert.
__global__ void cvt_hist_kernel(const float* __restrict__ in, uint4* __restrict__ out,
                                const int* __restrict__ head, int* __restrict__ cnt) {
    const int b = blockIdx.x;
    if (b < HIST_BLOCKS) {
        const int tid = b * 256 + threadIdx.x;
        if (tid < EQ4) {
            atomicAdd(&cnt[head[tid]], 1);
            atomicAdd(&cnt[head[tid + EQ4]], 1);
            atomicAdd(&cnt[head[tid + 2 * EQ4]], 1);
            atomicAdd(&cnt[head[tid + 3 * EQ4]], 1);
        }
    } else {
        for (int i = (b - HIST_BLOCKS) * 256 + threadIdx.x; i < N8; i += CVT_BLOCKS * 256) {
            const float4 a = ((const float4*)in)[2 * i];
            const float4 c = ((const float4*)in)[2 * i + 1];
            uint4 o;
            o.x = bf16rne(a.x) | (bf16rne(a.y) << 16);
            o.y = bf16rne(a.z) | (bf16rne(a.w) << 16);
            o.z = bf16rne(c.x) | (bf16rne(c.y) << 16);
            o.w = bf16rne(c.z) | (bf16rne(c.w) << 16);
            out[i] = o;
        }
    }
}

// ---------------- CSR scan ----------------

__global__ void scan_part(const int* __restrict__ cnt, int* __restrict__ bsum, int N) {
    __shared__ int lds[256];
    const int t = threadIdx.x;
    const int i = blockIdx.x * 256 + t;
    lds[t] = (i < N) ? cnt[i] : 0;
    __syncthreads();
    for (int off = 128; off; off >>= 1) {
        if (t < off) lds[t] += lds[t + off];
        __syncthreads();
    }
    if (t == 0) bsum[blockIdx.x] = lds[0];
}

__global__ void scan_bsum(int* __restrict__ bsum, int nb) {
    __shared__ int lds[512];
    const int t = threadIdx.x;
    const int v = (t < nb) ? bsum[t] : 0;
    lds[t] = v;
    __syncthreads();
    for (int off = 1; off < 512; off <<= 1) {
        int u = (t >= off) ? lds[t - off] : 0;
        __syncthreads();
        lds[t] += u;
        __syncthreads();
    }
    if (t < nb) bsum[t] = lds[t] - v;   // exclusive
}

// writes row_ptr AND next (the atomic fill cursor, preloaded with row starts)
__global__ void scan_final(const int* __restrict__ cnt, const int* __restrict__ bsum,
                           int* __restrict__ row_ptr, int* __restrict__ next, int N) {
    __shared__ int lds[256];
    const int t = threadIdx.x;
    const int i = blockIdx.x * 256 + t;
    const int v = (i < N) ? cnt[i] : 0;
    lds[t] = v;
    __syncthreads();
    for (int off = 1; off < 256; off <<= 1) {
        int u = (t >= off) ? lds[t - off] : 0;
        __syncthreads();
        lds[t] += u;
        __syncthreads();
    }
    const int excl = lds[t] - v + bsum[blockIdx.x];
    if (i < N) { row_ptr[i] = excl; next[i] = excl; }
    if (i == N - 1) row_ptr[N] = excl + v;
}

// 8 edges per thread; atomicAdd(&next[h],1) yields the slot directly.
__global__ void fill_kernel(const int* __restrict__ head, const int* __restrict__ tail,
                            const int* __restrict__ etype, int* __restrict__ next,
                            int* __restrict__ packed) {
    const int tid = blockIdx.x * blockDim.x + threadIdx.x;
    if (tid >= EQ8) return;
    int h[8], pk[8], s[8];
    #pragma unroll
    for (int k = 0; k < 8; ++k) {
        const int ee = tid + k * EQ8;
        h[k]  = head[ee];
        pk[k] = tail[ee] | (etype[ee] << 20);
    }
    #pragma unroll
    for (int k = 0; k < 8; ++k) s[k] = atomicAdd(&next[h[k]], 1);
    #pragma unroll
    for (int k = 0; k < 8; ++k) packed[s[k]] = pk[k];
}

// ---------------- fused hop (bf16 state, group-per-node) ----------------
// 4 nodes per wave: each 16-lane group owns ONE node, walks all its edges.
// Lane p (0..15) owns dims [8p, 8p+8). Accumulate fp32; each lane holds the
// full edge-sum for its dims (no cross-group fold). ss-fold = 4 in-group
// shfl_xor. All 64 lanes store.
// SHFL SAFETY: broadcasts source only SAME-group lanes; trip count is
// group-uniform, so ds_bpermute never sources an exec-off lane.

#define HOP_GATHER_BODY                                                        \
    const int lane = threadIdx.x & 63;                                         \
    const int wave = (int)((blockIdx.x * blockDim.x + threadIdx.x) >> 6);      \
    const int g = lane >> 4;                                                   \
    const int p = lane & 15;                                                   \
    const int wid = wave * 4 + g;                                              \
    if (wid >= N) return;                                                      \
    const int beg = row_ptr[wid];                                              \
    const int deg = row_ptr[wid + 1] - beg;                                    \
    const float4* __restrict__ rel4 = (const float4*)rel;                      \
    const int d0 = min(deg, 16);                                               \
    const int pv = (p < d0) ? packed[beg + p] : 0;                             \
    const int gbase = lane & 48;                                               \
    float4 accA = make_float4(0.f, 0.f, 0.f, 0.f);                             \
    float4 accB = make_float4(0.f, 0.f, 0.f, 0.f);                             \
    for (int e = 0; e < d0; ++e) {                                             \
        const int pk = __shfl(pv, gbase + e, 64);                              \
        const int t = pk & 0xFFFFF;                                            \
        const int r = pk >> 20;                                                \
        const uint4  xv = xb[t * 16 + p];                                      \
        const float4 ra = rel4[r * 32 + 2 * p];                                \
        const float4 rb = rel4[r * 32 + 2 * p + 1];                            \
        accA.x = fmaf(bflo(xv.x), ra.x, accA.x);                               \
        accA.y = fmaf(bfhi(xv.x), ra.y, accA.y);                               \
        accA.z = fmaf(bflo(xv.y), ra.z, accA.z);                               \
        accA.w = fmaf(bfhi(xv.y), ra.w, accA.w);                               \
        accB.x = fmaf(bflo(xv.z), rb.x, accB.x);                               \
        accB.y = fmaf(bfhi(xv.z), rb.y, accB.y);                               \
        accB.z = fmaf(bflo(xv.w), rb.z, accB.z);                               \
        accB.w = fmaf(bfhi(xv.w), rb.w, accB.w);                               \
    }                                                                          \
    for (int e = 16; e < deg; ++e) {                                           \
        const int pk = packed[beg + e];                                        \
        const int t = pk & 0xFFFFF;                                            \
        const int r = pk >> 20;                                                \
        const uint4  xv = xb[t * 16 + p];                                      \
        const float4 ra = rel4[r * 32 + 2 * p];                                \
        const float4 rb = rel4[r * 32 + 2 * p + 1];                            \
        accA.x = fmaf(bflo(xv.x), ra.x, accA.x);                               \
        accA.y = fmaf(bfhi(xv.x), ra.y, accA.y);                               \
        accA.z = fmaf(bflo(xv.y), ra.z, accA.z);                               \
        accA.w = fmaf(bfhi(xv.y), ra.w, accA.w);                               \
        accB.x = fmaf(bflo(xv.z), rb.x, accB.x);                               \
        accB.y = fmaf(bfhi(xv.z), rb.y, accB.y);                               \
        accB.z = fmaf(bflo(xv.w), rb.z, accB.z);                               \
        accB.w = fmaf(bfhi(xv.w), rb.w, accB.w);                               \
    }                                                                          \
    const float inv = 1.0f / (float)max(deg, 1);                               \
    accA.x *= inv; accA.y *= inv; accA.z *= inv; accA.w *= inv;                \
    accB.x *= inv; accB.y *= inv; accB.z *= inv; accB.w *= inv;                \
    float ss = accA.x * accA.x + accA.y * accA.y + accA.z * accA.z             \
             + accA.w * accA.w + accB.x * accB.x + accB.y * accB.y             \
             + accB.z * accB.z + accB.w * accB.w;                              \
    _Pragma("unroll")                                                          \
    for (int off = 8; off; off >>= 1) ss += __shfl_xor(ss, off, 64);           \
    const float scale = 1.0f / fmaxf(sqrtf(ss), EPSF);

__global__ __launch_bounds__(256) void hop_kernel(
    const uint4* __restrict__ xb, const float* __restrict__ rel,
    const int* __restrict__ row_ptr, const int* __restrict__ packed,
    uint4* __restrict__ xn, int N) {

    HOP_GATHER_BODY

    uint4 o;
    o.x = bf16rne(accA.x * scale) | (bf16rne(accA.y * scale) << 16);
    o.y = bf16rne(accA.z * scale) | (bf16rne(accA.w * scale) << 16);
    o.z = bf16rne(accB.x * scale) | (bf16rne(accB.y * scale) << 16);
    o.w = bf16rne(accB.z * scale) | (bf16rne(accB.w * scale) << 16);
    xn[wid * 16 + p] = o;
}

// hop 3 fused with the residual sum: res = ego + x1 + x2 + x3 (fp32 out).
// ego is read in bf16 (egob) to halve its HBM stream; adds ~2^-9 abs error.
__global__ __launch_bounds__(256) void hop_final_kernel(
    const uint4* __restrict__ xb, const float* __restrict__ rel,
    const int* __restrict__ row_ptr, const int* __restrict__ packed,
    const uint4* __restrict__ egob, const uint4* __restrict__ x1,
    const uint4* __restrict__ x2, float* __restrict__ res, int N) {

    HOP_GATHER_BODY

    const uint4 ue = egob[wid * 16 + p];
    const uint4 u1 = x1[wid * 16 + p];
    const uint4 u2 = x2[wid * 16 + p];
    float4 o0, o1;
    o0.x = bflo(ue.x) + bflo(u1.x) + bflo(u2.x) + accA.x * scale;
    o0.y = bfhi(ue.x) + bfhi(u1.x) + bfhi(u2.x) + accA.y * scale;
    o0.z = bflo(ue.y) + bflo(u1.y) + bflo(u2.y) + accA.z * scale;
    o0.w = bfhi(ue.y) + bfhi(u1.y) + bfhi(u2.y) + accA.w * scale;
    o1.x = bflo(ue.z) + bflo(u1.z) + bflo(u2.z) + accB.x * scale;
    o1.y = bfhi(ue.z) + bfhi(u1.z) + bfhi(u2.z) + accB.y * scale;
    o1.z = bflo(ue.w) + bflo(u1.w) + bflo(u2.w) + accB.z * scale;
    o1.w = bfhi(ue.w) + bfhi(u1.w) + bfhi(u2.w) + accB.w * scale;
    ((float4*)res)[wid * 32 + 2 * p]     = o0;
    ((float4*)res)[wid * 32 + 2 * p + 1] = o1;
}

// ---------------- launch ----------------

extern "C" void kernel_launch(void* const* d_in, const int* in_sizes, int n_in,
                              void* d_out, int out_size, void* d_ws, size_t ws_size,
                              hipStream_t stream) {
    const float* ego   = (const float*)d_in[0];
    const int*   eidx  = (const int*)d_in[1];   // [2, E]: row 0 = head, row 1 = tail
    const int*   etype = (const int*)d_in[2];
    const float* rel   = (const float*)d_in[3];
    // d_in[4] = dropout scalar (0 in eval) -> ignored

    const int* head = eidx;
    const int* tail = eidx + N_EDGES;
    float* res = (float*)d_out;

    // workspace layout
    char* ws = (char*)d_ws;
    int* cnt     = (int*)ws;  ws += (size_t)N_NODES * sizeof(int);
    int* row_ptr = (int*)ws;  ws += (size_t)(N_NODES + 1) * sizeof(int);
    int* next    = (int*)ws;  ws += (size_t)N_NODES * sizeof(int);
    int* packed  = (int*)ws;  ws += (size_t)N_EDGES * sizeof(int);
    int* bsum    = (int*)ws;  ws += (size_t)SCAN_NBLK * sizeof(int);
    ws = (char*)(((uintptr_t)ws + 255) & ~(uintptr_t)255);
    const size_t xbytes = (size_t)N_NODES * EMBED_DIM * 2;   // bf16
    uint4* egob = (uint4*)ws;  ws += xbytes;
    uint4* xb1  = (uint4*)ws;  ws += xbytes;
    uint4* xb2  = (uint4*)ws;

    const int n4cnt = (N_NODES * 4 + 15) / 16;   // uint4 count for cnt
    zero_kernel<<<(n4cnt + 255) / 256, 256, 0, stream>>>((uint4*)cnt, n4cnt);

    cvt_hist_kernel<<<HIST_BLOCKS + CVT_BLOCKS, 256, 0, stream>>>(ego, egob, head, cnt);
    scan_part <<<SCAN_NBLK, 256, 0, stream>>>(cnt, bsum, N_NODES);
    scan_bsum <<<1, 512, 0, stream>>>(bsum, SCAN_NBLK);
    scan_final<<<SCAN_NBLK, 256, 0, stream>>>(cnt, bsum, row_ptr, next, N_NODES);
    fill_kernel<<<(EQ8 + 255) / 256, 256, 0, stream>>>(head, tail, etype, next, packed);

    // 4 nodes per wave -> 16 nodes per 256-thread block
    const int nblocks = (N_NODES + 15) / 16;
    hop_kernel<<<nblocks, 256, 0, stream>>>(egob, rel, row_ptr, packed, xb1, N_NODES);
    hop_kernel<<<nblocks, 256, 0, stream>>>(xb1,  rel, row_ptr, packed, xb2, N_NODES);
    hop_final_kernel<<<nblocks, 256, 0, stream>>>(xb2, rel, row_ptr, packed,
                                                  egob, xb1, xb2, res, N_NODES);
}